// Round 5
// baseline (189.714 us; speedup 1.0000x reference)
//
#include <hip/hip_runtime.h>
#include <math.h>

#define BB 16
#define NN 8
#define KK 2048
#define DD 512
#define CC 11
#define BN (BB*NN)          // 128
#define NCHUNK 16
#define KCHUNK (KK/NCHUNK)  // 128 vectors per block
#define NBLK (BN*NCHUNK)    // 2048
#define EPSN 1e-12f
#define ALPHA 0.9f

typedef float fx4 __attribute__((ext_vector_type(4)));

__device__ __forceinline__ int clamp_cat(int c) {
    c = c - 1;
    return c < 0 ? 0 : (c > 10 ? 10 : c);
}

// Fused kernel: sim_pos + masked exp-sum over negatives + last-block final
// reduction. NBLK blocks x 256 threads. Each wave processes 2 k-vectors per
// iteration via 32-lane groups; depth-1 prefetch keeps 4 dwordx4 NT loads in
// flight across the compute+shuffle chain.
__global__ __launch_bounds__(256)
void k2_neg(const float* __restrict__ pred, const float* __restrict__ pos,
            const float* __restrict__ neg, const float* __restrict__ centers,
            const int* __restrict__ cats,
            float* __restrict__ simpos, float* __restrict__ partials,
            unsigned int* __restrict__ counter, float* __restrict__ out) {
    int blk   = blockIdx.x;
    int bn    = blk / NCHUNK;
    int chunk = blk % NCHUNK;
    int b     = bn / NN;
    int wave  = threadIdx.x >> 6;
    int l     = threadIdx.x & 63;
    int g     = l >> 5;       // vector-of-pair select
    int sub   = l & 31;       // lane within 32-group

    int cat = clamp_cat(cats[bn]);

    const float4* c4 = (const float4*)(centers + (size_t)cat * DD);
    const float4* p4 = (const float4*)(pred + ((size_t)b * CC + cat) * DD);
    const float4* q4 = (const float4*)(pos + (size_t)bn * DD);

    // per-lane slice (16 floats) of center and pred-center; fused sim_pos
    float cc[16], pn[16];
    float ssa = 0.f, ssp = 0.f, dap = 0.f;
    #pragma unroll
    for (int j = 0; j < 4; ++j) {
        float4 cv = c4[sub + j * 32];
        float4 pv = p4[sub + j * 32];
        float4 qv = q4[sub + j * 32];
        cc[j*4+0] = cv.x; cc[j*4+1] = cv.y; cc[j*4+2] = cv.z; cc[j*4+3] = cv.w;
        float a0 = pv.x - cv.x, a1 = pv.y - cv.y, a2 = pv.z - cv.z, a3 = pv.w - cv.w;
        float q0 = qv.x - cv.x, q1 = qv.y - cv.y, q2 = qv.z - cv.z, q3 = qv.w - cv.w;
        pn[j*4+0] = a0; pn[j*4+1] = a1; pn[j*4+2] = a2; pn[j*4+3] = a3;
        ssa += a0*a0 + a1*a1 + a2*a2 + a3*a3;
        ssp += q0*q0 + q1*q1 + q2*q2 + q3*q3;
        dap += a0*q0 + a1*q1 + a2*q2 + a3*q3;
    }
    #pragma unroll
    for (int off = 1; off < 32; off <<= 1) {
        ssa += __shfl_xor(ssa, off, 64);
        ssp += __shfl_xor(ssp, off, 64);
        dap += __shfl_xor(dap, off, 64);
    }
    float ia = 1.0f / sqrtf(fmaxf(ssa, EPSN));
    float ib = 1.0f / sqrtf(fmaxf(ssp, EPSN));
    float sp = dap * ia * ib;
    #pragma unroll
    for (int j = 0; j < 16; ++j) pn[j] *= ia;

    if (chunk == 0 && threadIdx.x == 0) simpos[bn] = sp;

    float acc = 0.f;

    const fx4* nb4 = (const fx4*)(neg + ((size_t)bn * KK + (size_t)chunk * KCHUNK) * DD);
    const int V4 = DD / 4;  // 128 float4 per vector

    fx4 cur[4];
    {
        const fx4* vb = nb4 + (size_t)(2 * wave + g) * V4;
        #pragma unroll
        for (int j = 0; j < 4; ++j) cur[j] = __builtin_nontemporal_load(&vb[sub + j * 32]);
    }

    auto process = [&](const fx4* v) {
        float ds = 0.f, s2 = 0.f;
        #pragma unroll
        for (int j = 0; j < 4; ++j) {
            #pragma unroll
            for (int e = 0; e < 4; ++e) {
                float d = v[j][e] - cc[j*4+e];
                ds += pn[j*4+e] * d;
                s2 += d * d;
            }
        }
        #pragma unroll
        for (int off = 1; off < 32; off <<= 1) {
            ds += __shfl_xor(ds, off, 64);
            s2 += __shfl_xor(s2, off, 64);
        }
        float sn = ds * (1.0f / sqrtf(fmaxf(s2, EPSN)));
        if (sub == 0 && (sn - sp >= ALPHA * sp)) acc += expf(sn);
    };

    for (int it = 0; it < 15; ++it) {
        fx4 nxt[4];
        const fx4* vb = nb4 + (size_t)(2 * (wave + 4 * (it + 1)) + g) * V4;
        #pragma unroll
        for (int j = 0; j < 4; ++j) nxt[j] = __builtin_nontemporal_load(&vb[sub + j * 32]);

        process(cur);

        #pragma unroll
        for (int j = 0; j < 4; ++j) cur[j] = nxt[j];
    }
    process(cur);  // it = 15 (peeled)

    // lanes 0 and 32 hold the two group partials
    acc += __shfl_xor(acc, 32, 64);

    __shared__ float sacc[4];
    if (l == 0) sacc[wave] = acc;
    __syncthreads();
    if (threadIdx.x == 0)
        partials[blk] = sacc[0] + sacc[1] + sacc[2] + sacc[3];

    // ---- last-block final reduction ----
    __shared__ bool amLast;
    if (threadIdx.x == 0) {
        __threadfence();                       // partials/simpos visible device-wide
        unsigned int old = atomicAdd(counter, 1u);
        amLast = (old == (unsigned int)(NBLK - 1));
    }
    __syncthreads();
    if (amLast) {
        __threadfence();                       // acquire all blocks' writes
        int t = threadIdx.x;
        float loss = 0.f;
        if (t < BN) {
            float ns = 0.f;
            #pragma unroll
            for (int i = 0; i < NCHUNK; ++i)
                ns += partials[t * NCHUNK + i];
            float spv = simpos[t];
            float ep = expf(spv);
            float denom = fmaxf(ep + ns, 1e-7f);
            loss = -logf(ep / denom);
        }
        __shared__ float s[BN];
        if (t < BN) s[t] = loss;
        __syncthreads();
        #pragma unroll
        for (int st = 64; st > 0; st >>= 1) {
            if (t < st) s[t] += s[t + st];
            __syncthreads();
        }
        if (t == 0) out[0] = s[0] / (float)BN;
    }
}

extern "C" void kernel_launch(void* const* d_in, const int* in_sizes, int n_in,
                              void* d_out, int out_size, void* d_ws, size_t ws_size,
                              hipStream_t stream) {
    const float* pred    = (const float*)d_in[0];  // (B, C, D)
    const float* pos     = (const float*)d_in[1];  // (B, N, D)
    const float* neg     = (const float*)d_in[2];  // (B, N, K, D)
    const float* centers = (const float*)d_in[3];  // (C, D)
    const int*   cats    = (const int*)d_in[4];    // (B, N)

    float* out = (float*)d_out;

    float*        simpos   = (float*)d_ws;                 // 128 floats
    float*        partials = simpos + BN;                  // 2048 floats
    unsigned int* counter  = (unsigned int*)(partials + NBLK);  // 1 uint

    hipMemsetAsync(counter, 0, sizeof(unsigned int), stream);
    k2_neg<<<NBLK, 256, 0, stream>>>(pred, pos, neg, centers, cats,
                                     simpos, partials, counter, out);
}

// Round 6
// 91.886 us; speedup vs baseline: 2.0647x; 2.0647x over previous
//
#include <hip/hip_runtime.h>
#include <math.h>

#define BB 16
#define NN 8
#define KK 2048
#define DD 512
#define CC 11
#define BN (BB*NN)          // 128
#define NCHUNK 16
#define KCHUNK (KK/NCHUNK)  // 128 vectors per block
#define EPSN 1e-12f
#define ALPHA 0.9f

typedef float fx4 __attribute__((ext_vector_type(4)));

__device__ __forceinline__ int clamp_cat(int c) {
    c = c - 1;
    return c < 0 ? 0 : (c > 10 ? 10 : c);
}

// Kernel 2 (fused sim_pos): masked exp-sum over negatives.
// 128*NCHUNK blocks x 256 threads. Each wave processes 2 k-vectors per
// iteration via 32-lane groups; reduction = 5 xor stages shared by both
// vectors; depth-1 prefetch keeps 4 dwordx4 NT loads in flight across the
// compute+shuffle chain. NOTE: do NOT fuse the final reduction into this
// kernel — a device-scope fence per block (last-block pattern) triggers a
// per-block L2 writeback on multi-XCD gfx950 and cost +98 us (R5).
__global__ __launch_bounds__(256)
void k2_neg(const float* __restrict__ pred, const float* __restrict__ pos,
            const float* __restrict__ neg, const float* __restrict__ centers,
            const int* __restrict__ cats,
            float* __restrict__ simpos, float* __restrict__ partials) {
    int blk   = blockIdx.x;
    int bn    = blk / NCHUNK;
    int chunk = blk % NCHUNK;
    int b     = bn / NN;
    int wave  = threadIdx.x >> 6;
    int l     = threadIdx.x & 63;
    int g     = l >> 5;       // vector-of-pair select
    int sub   = l & 31;       // lane within 32-group

    int cat = clamp_cat(cats[bn]);

    const float4* c4 = (const float4*)(centers + (size_t)cat * DD);
    const float4* p4 = (const float4*)(pred + ((size_t)b * CC + cat) * DD);
    const float4* q4 = (const float4*)(pos + (size_t)bn * DD);

    // per-lane slice (16 floats) of center and pred-center; fused sim_pos
    float cc[16], pn[16];
    float ssa = 0.f, ssp = 0.f, dap = 0.f;
    #pragma unroll
    for (int j = 0; j < 4; ++j) {
        float4 cv = c4[sub + j * 32];
        float4 pv = p4[sub + j * 32];
        float4 qv = q4[sub + j * 32];
        cc[j*4+0] = cv.x; cc[j*4+1] = cv.y; cc[j*4+2] = cv.z; cc[j*4+3] = cv.w;
        float a0 = pv.x - cv.x, a1 = pv.y - cv.y, a2 = pv.z - cv.z, a3 = pv.w - cv.w;
        float q0 = qv.x - cv.x, q1 = qv.y - cv.y, q2 = qv.z - cv.z, q3 = qv.w - cv.w;
        pn[j*4+0] = a0; pn[j*4+1] = a1; pn[j*4+2] = a2; pn[j*4+3] = a3;
        ssa += a0*a0 + a1*a1 + a2*a2 + a3*a3;
        ssp += q0*q0 + q1*q1 + q2*q2 + q3*q3;
        dap += a0*q0 + a1*q1 + a2*q2 + a3*q3;
    }
    #pragma unroll
    for (int off = 1; off < 32; off <<= 1) {
        ssa += __shfl_xor(ssa, off, 64);
        ssp += __shfl_xor(ssp, off, 64);
        dap += __shfl_xor(dap, off, 64);
    }
    float ia = 1.0f / sqrtf(fmaxf(ssa, EPSN));
    float ib = 1.0f / sqrtf(fmaxf(ssp, EPSN));
    float sp = dap * ia * ib;
    #pragma unroll
    for (int j = 0; j < 16; ++j) pn[j] *= ia;

    if (chunk == 0 && threadIdx.x == 0) simpos[bn] = sp;

    float acc = 0.f;

    const fx4* nb4 = (const fx4*)(neg + ((size_t)bn * KK + (size_t)chunk * KCHUNK) * DD);
    const int V4 = DD / 4;  // 128 float4 per vector

    fx4 cur[4];
    {
        const fx4* vb = nb4 + (size_t)(2 * wave + g) * V4;
        #pragma unroll
        for (int j = 0; j < 4; ++j) cur[j] = __builtin_nontemporal_load(&vb[sub + j * 32]);
    }

    auto process = [&](const fx4* v) {
        float ds = 0.f, s2 = 0.f;
        #pragma unroll
        for (int j = 0; j < 4; ++j) {
            #pragma unroll
            for (int e = 0; e < 4; ++e) {
                float d = v[j][e] - cc[j*4+e];
                ds += pn[j*4+e] * d;
                s2 += d * d;
            }
        }
        #pragma unroll
        for (int off = 1; off < 32; off <<= 1) {
            ds += __shfl_xor(ds, off, 64);
            s2 += __shfl_xor(s2, off, 64);
        }
        float sn = ds * (1.0f / sqrtf(fmaxf(s2, EPSN)));
        if (sub == 0 && (sn - sp >= ALPHA * sp)) acc += expf(sn);
    };

    for (int it = 0; it < 15; ++it) {
        fx4 nxt[4];
        const fx4* vb = nb4 + (size_t)(2 * (wave + 4 * (it + 1)) + g) * V4;
        #pragma unroll
        for (int j = 0; j < 4; ++j) nxt[j] = __builtin_nontemporal_load(&vb[sub + j * 32]);

        process(cur);

        #pragma unroll
        for (int j = 0; j < 4; ++j) cur[j] = nxt[j];
    }
    process(cur);  // it = 15 (peeled)

    // lanes 0 and 32 hold the two group partials
    acc += __shfl_xor(acc, 32, 64);

    __shared__ float sacc[4];
    if (l == 0) sacc[wave] = acc;
    __syncthreads();
    if (threadIdx.x == 0)
        partials[blk] = sacc[0] + sacc[1] + sacc[2] + sacc[3];
}

// Kernel 3: final loss mean. 1 block x 128 threads.
__global__ __launch_bounds__(128)
void k3_final(const float* __restrict__ simpos, const float* __restrict__ partials,
              float* __restrict__ out) {
    int bn = threadIdx.x;
    float ns = 0.f;
    for (int i = 0; i < NCHUNK; ++i)
        ns += partials[bn * NCHUNK + i];
    float sp = simpos[bn];
    float ep = expf(sp);
    float denom = fmaxf(ep + ns, 1e-7f);
    float loss = -logf(ep / denom);

    __shared__ float s[BN];
    s[bn] = loss;
    __syncthreads();
    #pragma unroll
    for (int st = 64; st > 0; st >>= 1) {
        if (bn < st) s[bn] += s[bn + st];
        __syncthreads();
    }
    if (bn == 0) out[0] = s[0] / (float)BN;
}

extern "C" void kernel_launch(void* const* d_in, const int* in_sizes, int n_in,
                              void* d_out, int out_size, void* d_ws, size_t ws_size,
                              hipStream_t stream) {
    const float* pred    = (const float*)d_in[0];  // (B, C, D)
    const float* pos     = (const float*)d_in[1];  // (B, N, D)
    const float* neg     = (const float*)d_in[2];  // (B, N, K, D)
    const float* centers = (const float*)d_in[3];  // (C, D)
    const int*   cats    = (const int*)d_in[4];    // (B, N)

    float* out = (float*)d_out;

    float* simpos   = (float*)d_ws;            // 128 floats
    float* partials = simpos + BN;             // 128*16 floats

    k2_neg<<<BN * NCHUNK, 256, 0, stream>>>(pred, pos, neg, centers, cats, simpos, partials);
    k3_final<<<1, 128, 0, stream>>>(simpos, partials, out);
}